// Round 6
// baseline (12.206 us; speedup 1.0000x reference)
//
#include <hip/hip_runtime.h>
#include <hip/hip_bf16.h>
#include <string.h>

// out[n][c] = -sum_f (x[n][f]-m[c][f])^2 = 2*x.m - |x|^2 - |m|^2
// N=2048, C=512, F=512, fp32 in/out.
//
// Single fused kernel, grid=256 (1 block/CU), 512 threads (8 waves -> 2
// waves/SIMD). 64x64 output tile, full K=512 in LDS (A 64KB + B 64KB bf16,
// XOR-swizzled both sides). Split-K: waves 0-3 own the four 32x32 output
// quadrants for K=0..255, waves 4-7 the same quadrants for K=256..511;
// partials combined through a stride-17-padded LDS region.
// Phase 1 batches ALL 32 float4 loads up front (one latency exposure) and
// converts with native __float22bfloat162_rn so the compiler emits
// v_cvt_pk_bf16_f32 (hardware RNE, 2 elem/inst) instead of 5-op bit math.

#define F_DIM  512
#define C_ROWS 512

typedef __attribute__((ext_vector_type(8))) short short8;
typedef __attribute__((ext_vector_type(4))) float f32x4;

static __device__ __forceinline__ unsigned pk_bf16(float lo, float hi) {
    __hip_bfloat162 h = __float22bfloat162_rn(make_float2(lo, hi));
    unsigned u;
    memcpy(&u, &h, 4);  // folds to a register move; h is a v_cvt_pk_bf16_f32
    return u;
}

__global__ __launch_bounds__(512) void ncm_fused(
        const float* __restrict__ x, const float* __restrict__ means,
        float* __restrict__ out) {
    // 64 rows x 512 bf16 each; row stride 1024B. 16B slots XOR-swizzled by
    // (row&7) on BOTH write (ds_write_b128) and read (ds_read_b128) sides.
    __shared__ __align__(16) short As[64 * 512];
    __shared__ __align__(16) short Bs[64 * 512];
    __shared__ float xn_s[64], mn_s[64];

    // Block -> tile mapping: XCD (d&7) owns 4 consecutive row-tiles so its L2
    // working set is 512KB of x + 1MB of means (fits 4MB/XCD L2).
    const int d  = blockIdx.x;                     // 0..255
    const int by = (d & 7) * 4 + ((d >> 3) & 3);   // 0..31
    const int bx = d >> 5;                         // 0..7
    const int rowBase = by * 64, colBase = bx * 64;

    const int t    = threadIdx.x;
    const int w    = t >> 6;      // 0..7
    const int lane = t & 63;
    const int qr   = lane >> 4;   // quarter-wave row offset
    const int ql   = lane & 15;   // lane within quarter-wave

    // ---------------- Phase 1: stage + convert + norms ----------------
    // Quarter-wave owns a row; a lane covers 8 contiguous floats per (i,ph)
    // -> one swizzled ds_write_b128. All 32 float4 loads issued before any
    // conversion: single global-latency exposure, hidden across 2 waves/SIMD.
    float4 va[2][2][4][2];  // [half][i][ph][lo/hi] = 128 VGPRs
#pragma unroll
    for (int half = 0; half < 2; half++) {
        const float* src = (half == 0) ? x + (size_t)rowBase * F_DIM
                                       : means + (size_t)colBase * F_DIM;
#pragma unroll
        for (int i = 0; i < 2; i++) {
            const float* rowp = src + (size_t)(w * 8 + i * 4 + qr) * F_DIM;
#pragma unroll
            for (int ph = 0; ph < 4; ph++) {
                const float* p = rowp + ph * 128 + ql * 8;
                va[half][i][ph][0] = *(const float4*)p;
                va[half][i][ph][1] = *(const float4*)(p + 4);
            }
        }
    }

#pragma unroll
    for (int half = 0; half < 2; half++) {
        short* dst  = (half == 0) ? As : Bs;
        float* nrm  = (half == 0) ? xn_s : mn_s;
#pragma unroll
        for (int i = 0; i < 2; i++) {
            const int r = w * 8 + i * 4 + qr;
            float ss = 0.f;
#pragma unroll
            for (int ph = 0; ph < 4; ph++) {
                float vv[8] = {va[half][i][ph][0].x, va[half][i][ph][0].y,
                               va[half][i][ph][0].z, va[half][i][ph][0].w,
                               va[half][i][ph][1].x, va[half][i][ph][1].y,
                               va[half][i][ph][1].z, va[half][i][ph][1].w};
                int4 o;  // 8 bf16 = 4x v_cvt_pk_bf16_f32 (hardware RNE)
                o.x = (int)pk_bf16(vv[0], vv[1]);
                o.y = (int)pk_bf16(vv[2], vv[3]);
                o.z = (int)pk_bf16(vv[4], vv[5]);
                o.w = (int)pk_bf16(vv[6], vv[7]);
#pragma unroll
                for (int j = 0; j < 8; j++) ss += vv[j] * vv[j];
                const int slot = ph * 16 + ql;
                *(int4*)(dst + r * F_DIM + ((slot ^ (r & 7)) << 3)) = o;
            }
            ss += __shfl_xor(ss, 1);
            ss += __shfl_xor(ss, 2);
            ss += __shfl_xor(ss, 4);
            ss += __shfl_xor(ss, 8);
            if (ql == 0) nrm[r] = ss;
        }
    }
    __syncthreads();

    // ---------------- Phase 2: MFMA, split-K across wave groups ----------
    const int quad = w & 3;       // output quadrant
    const int kh   = w >> 2;      // K-half: 0 -> K 0..255, 1 -> K 256..511
    const int wr   = (quad >> 1) * 32;
    const int wc   = (quad & 1) * 32;

    f32x4 acc[2][2];
#pragma unroll
    for (int mi = 0; mi < 2; mi++)
#pragma unroll
        for (int ni = 0; ni < 2; ni++)
            acc[mi][ni] = (f32x4){0.f, 0.f, 0.f, 0.f};

#pragma unroll
    for (int j = 0; j < 8; j++) {
        const int kk   = kh * 8 + j;
        const int slot = kk * 4 + (lane >> 4);
        short8 a[2], b[2];
#pragma unroll
        for (int mi = 0; mi < 2; mi++) {
            const int r = wr + mi * 16 + (lane & 15);
            a[mi] = *(const short8*)(As + r * F_DIM + ((slot ^ (r & 7)) << 3));
        }
#pragma unroll
        for (int ni = 0; ni < 2; ni++) {
            const int r = wc + ni * 16 + (lane & 15);
            b[ni] = *(const short8*)(Bs + r * F_DIM + ((slot ^ (r & 7)) << 3));
        }
#pragma unroll
        for (int mi = 0; mi < 2; mi++)
#pragma unroll
            for (int ni = 0; ni < 2; ni++)
                acc[mi][ni] = __builtin_amdgcn_mfma_f32_16x16x32_bf16(
                    a[mi], b[ni], acc[mi][ni], 0, 0, 0);
    }

    // ---------------- Split-K combine via padded LDS (reuse As) ----------
    __syncthreads();  // all ds_reads of As/Bs done before aliasing As
    float* red = (float*)As;
    if (kh == 1) {
#pragma unroll
        for (int mi = 0; mi < 2; mi++)
#pragma unroll
            for (int ni = 0; ni < 2; ni++)
#pragma unroll
                for (int j = 0; j < 4; j++)
                    red[quad * 1088 + lane * 17 + mi * 8 + ni * 4 + j] =
                        acc[mi][ni][j];
    }
    __syncthreads();
    if (kh == 0) {
#pragma unroll
        for (int mi = 0; mi < 2; mi++)
#pragma unroll
            for (int ni = 0; ni < 2; ni++)
#pragma unroll
                for (int j = 0; j < 4; j++)
                    acc[mi][ni][j] +=
                        red[quad * 1088 + lane * 17 + mi * 8 + ni * 4 + j];

        // ---------------- Epilogue: out = 2*acc - |x|^2 - |m|^2 ----------
        // C/D layout: col = lane&15, row = (lane>>4)*4 + j.
        float xn[2][4];
#pragma unroll
        for (int mi = 0; mi < 2; mi++)
#pragma unroll
            for (int j = 0; j < 4; j++)
                xn[mi][j] = xn_s[wr + mi * 16 + (lane >> 4) * 4 + j];

#pragma unroll
        for (int ni = 0; ni < 2; ni++) {
            const int cl = wc + ni * 16 + (lane & 15);
            const int c  = colBase + cl;
            const float mn = mn_s[cl];
#pragma unroll
            for (int mi = 0; mi < 2; mi++) {
                const int rbase = rowBase + wr + mi * 16 + (lane >> 4) * 4;
#pragma unroll
                for (int j = 0; j < 4; j++)
                    out[(size_t)(rbase + j) * C_ROWS + c] =
                        2.0f * acc[mi][ni][j] - xn[mi][j] - mn;
            }
        }
    }
}

extern "C" void kernel_launch(void* const* d_in, const int* in_sizes, int n_in,
                              void* d_out, int out_size, void* d_ws, size_t ws_size,
                              hipStream_t stream) {
    const float* x     = (const float*)d_in[0];
    const float* means = (const float*)d_in[1];
    float* out = (float*)d_out;
    ncm_fused<<<256, 512, 0, stream>>>(x, means, out);
}